// Round 9
// baseline (613.253 us; speedup 1.0000x reference)
//
#include <hip/hip_runtime.h>

#define NN 40000
#define NPAD 40064          // 313 * 128
#define EE 640000
#define KDIN 128
#define KDOUT 256

#define NBIN 157            // coarse buckets: dst >> 8, and edge chunks of 4096
#define BCAP 5120           // LDS bucket capacity (mean 4076, sigma 64 -> +16 sigma)

typedef __attribute__((ext_vector_type(8))) short bf16x8;   // 8 bf16 = 4 VGPR
typedef __attribute__((ext_vector_type(4))) float f32x4;    // MFMA acc

static __device__ __forceinline__ unsigned short f2bf(float f) {
    union { float f; unsigned int u; } v; v.f = f;
    unsigned int r = (v.u + 0x7FFFu + ((v.u >> 16) & 1u)) >> 16;  // RNE
    return (unsigned short)r;
}
static __device__ __forceinline__ float bf2f(unsigned short h) {
    union { unsigned int u; float f; } v; v.u = ((unsigned int)h) << 16;
    return v.f;
}

// ------------------------------------------------------------------ front
// One kernel, independent block-range jobs (no intra-kernel dependencies):
//   [0, 157)       : edge binning — sort 4096-edge chunk by dst>>8 in LDS,
//                    write sorted recs (coalesced) + per-bucket offsets lmat
//   [157, 2661)    : x -> bf16 (NPAD rows; pad rows = 0)
//   [2661, 3173)   : W1/W2/Wres transpose+convert -> w1t|w2t|wrt (concat)
//   [3173, 3177)   : hb pad rows = 0
// Record: (dst & 255) << 16 | src   (src < 65536)
#define FRONT_GRID 3177
__global__ __launch_bounds__(256) void k_front(
    const float* __restrict__ x,
    const float* __restrict__ W1, const float* __restrict__ W2,
    const float* __restrict__ Wres, const int* __restrict__ ei,
    ushort* __restrict__ xb, ushort* __restrict__ wt_all,
    unsigned int* __restrict__ recs, int* __restrict__ lmat,
    ushort* __restrict__ hb) {
    __shared__ unsigned int SM[4096 + 480 + 256];    // 19.3 KB, binning branch only
    int b = blockIdx.x, tid = threadIdx.x;
    if (b < NBIN) {                                  // ---- edge binning
        unsigned int* lrec = SM;
        int* cnt    = (int*)(SM + 4096);
        int* lstart = cnt + 160;
        int* lcur   = lstart + 160;
        int* sw     = lcur + 160;                    // [256]
        int e0 = b * 4096;
        int ns = min(e0 + 4096, EE) - e0;

        if (tid < NBIN) cnt[tid] = 0;
        __syncthreads();
        for (int s = tid; s < ns; s += 256)
            atomicAdd(&cnt[ei[EE + e0 + s] >> 8], 1);
        __syncthreads();
        sw[tid] = (tid < NBIN) ? cnt[tid] : 0;
        __syncthreads();
        for (int off = 1; off < 256; off <<= 1) {
            int add = (tid >= off) ? sw[tid - off] : 0;
            __syncthreads();
            sw[tid] += add;
            __syncthreads();
        }
        if (tid < NBIN) {
            int st = sw[tid] - cnt[tid];
            lstart[tid] = st;
            lcur[tid] = st;
        }
        __syncthreads();
        for (int s = tid; s < ns; s += 256) {
            int e = e0 + s;
            int src = ei[e];
            int dst = ei[EE + e];
            int p = atomicAdd(&lcur[dst >> 8], 1);
            lrec[p] = ((unsigned int)(dst & 255) << 16) | (unsigned int)src;
        }
        __syncthreads();
        for (int s = tid; s < ns; s += 256)          // coalesced sorted chunk
            recs[b * 4096 + s] = lrec[s];
        if (tid < NBIN + 1)
            lmat[b * 158 + tid] = (tid < NBIN) ? lstart[tid] : ns;
    } else if (b < 2661) {                           // ---- x convert
        int i = (b - NBIN) * 256 + tid;              // elem8 index
        int row = i >> 4;
        uint4 o = {0, 0, 0, 0};
        if (row < NN) {
            const float4* xp = (const float4*)x + (size_t)i * 2;
            float4 a = xp[0], c = xp[1];
            o.x = (unsigned)f2bf(a.x) | ((unsigned)f2bf(a.y) << 16);
            o.y = (unsigned)f2bf(a.z) | ((unsigned)f2bf(a.w) << 16);
            o.z = (unsigned)f2bf(c.x) | ((unsigned)f2bf(c.y) << 16);
            o.w = (unsigned)f2bf(c.z) | ((unsigned)f2bf(c.w) << 16);
        }
        if (row < NPAD) *(uint4*)(xb + (size_t)i * 8) = o;
    } else if (b < 3173) {                           // ---- weight transposes
        int j = (b - 2661) * 256 + tid;              // concat index
        if (j < 32768) {                             // w1t [256][128]
            int c = j >> 7, r = j & 127;
            wt_all[j] = f2bf(W1[r * KDOUT + c]);
        } else if (j < 98304) {                      // w2t [256][256]
            int j2 = j - 32768;
            int c = j2 >> 8, r = j2 & 255;
            wt_all[j] = f2bf(W2[r * KDOUT + c]);
        } else {                                     // wrt [256][128]
            int j3 = j - 98304;
            int c = j3 >> 7, r = j3 & 127;
            wt_all[j] = f2bf(Wres[r * KDOUT + c]);
        }
    } else {                                         // ---- hb pad rows = 0
        int idx = (b - 3173) * 256 + tid;            // 1024 uint4 = 16 KB
        ((uint4*)(hb + (size_t)NN * KDIN))[idx] = (uint4){0, 0, 0, 0};
    }
}

// ------------------------------- aggregate: LDS fp32 atomic accumulation
// Grid NBIN*4: blockIdx = b*4 + q  (q: dim-quarter, 32 dims).
// acc[256][33] fp32 (pad 33 -> ds_add bank = (d8+k)&31, random d8 ~2-way).
// 1) init acc = (1+eps)*x  2) coalesced pack of bucket b into lrec
// 3) 4 lanes/record: 16B x load + 8 ds_add each  4) writeout bf16.
#define ADD8(ap_, v_)                                                           \
    atomicAdd((ap_) + 0, bf2f((ushort)((v_).x & 0xffff)));                      \
    atomicAdd((ap_) + 1, bf2f((ushort)((v_).x >> 16)));                         \
    atomicAdd((ap_) + 2, bf2f((ushort)((v_).y & 0xffff)));                      \
    atomicAdd((ap_) + 3, bf2f((ushort)((v_).y >> 16)));                         \
    atomicAdd((ap_) + 4, bf2f((ushort)((v_).z & 0xffff)));                      \
    atomicAdd((ap_) + 5, bf2f((ushort)((v_).z >> 16)));                         \
    atomicAdd((ap_) + 6, bf2f((ushort)((v_).w & 0xffff)));                      \
    atomicAdd((ap_) + 7, bf2f((ushort)((v_).w >> 16)));

__global__ __launch_bounds__(256) void k_aggC(
    const unsigned int* __restrict__ recs, const int* __restrict__ lmat,
    const ushort* __restrict__ xb, const float* __restrict__ eps,
    ushort* __restrict__ hb) {
    __shared__ float acc[256 * 33];                  // 33.8 KB
    __shared__ unsigned int lrec[BCAP];              // 20 KB
    __shared__ int sw[256];
    int tid = threadIdx.x;
    int b = blockIdx.x >> 2, q = blockIdx.x & 3;
    int wid = tid >> 6, lane = tid & 63;
    float s1 = 1.0f + eps[0];

    // ---- init acc with self term
    int node = b * 256 + tid;
    if (node < NN) {
        const uint4* xr = (const uint4*)(xb + (size_t)node * KDIN + q * 32);
        float* ap = acc + tid * 33;
#pragma unroll
        for (int j = 0; j < 4; ++j) {
            uint4 v = xr[j];
            ap[j * 8 + 0] = bf2f((ushort)(v.x & 0xffff)) * s1;
            ap[j * 8 + 1] = bf2f((ushort)(v.x >> 16)) * s1;
            ap[j * 8 + 2] = bf2f((ushort)(v.y & 0xffff)) * s1;
            ap[j * 8 + 3] = bf2f((ushort)(v.y >> 16)) * s1;
            ap[j * 8 + 4] = bf2f((ushort)(v.z & 0xffff)) * s1;
            ap[j * 8 + 5] = bf2f((ushort)(v.z >> 16)) * s1;
            ap[j * 8 + 6] = bf2f((ushort)(v.w & 0xffff)) * s1;
            ap[j * 8 + 7] = bf2f((ushort)(v.w >> 16)) * s1;
        }
    }

    // ---- scan segment lengths (chunk-order prefix)
    int len0 = 0;
    if (tid < NBIN) len0 = lmat[tid * 158 + b + 1] - lmat[tid * 158 + b];
    sw[tid] = len0;
    __syncthreads();
    for (int off = 1; off < 256; off <<= 1) {
        int add = (tid >= off) ? sw[tid - off] : 0;
        __syncthreads();
        sw[tid] += add;
        __syncthreads();
    }
    int ctot = sw[255];

    // ---- coalesced pack: one wave per chunk, lanes along the segment
    for (int c = wid; c < NBIN; c += 4) {
        int s0 = lmat[c * 158 + b];
        int len = lmat[c * 158 + b + 1] - s0;
        int pofs = sw[c] - len;                      // exclusive prefix
        const unsigned int* seg = recs + c * 4096 + s0;
        for (int i = lane; i < len; i += 64)
            lrec[pofs + i] = seg[i];
    }
    __syncthreads();

    // ---- accumulate: 4 lanes per record, 2-way unrolled for MLP
    {
        int rg = tid >> 2, k4 = tid & 3;
        int i = rg;
        for (; i + 64 < ctot; i += 128) {
            unsigned int r0 = lrec[i], r1 = lrec[i + 64];
            int d0 = r0 >> 16, sA = r0 & 0xffff;
            int d1 = r1 >> 16, sB = r1 & 0xffff;
            uint4 v0 = *((const uint4*)(xb + (size_t)sA * KDIN + q * 32) + k4);
            uint4 v1 = *((const uint4*)(xb + (size_t)sB * KDIN + q * 32) + k4);
            float* a0 = acc + d0 * 33 + k4 * 8;
            float* a1 = acc + d1 * 33 + k4 * 8;
            ADD8(a0, v0);
            ADD8(a1, v1);
        }
        for (; i < ctot; i += 64) {
            unsigned int r0 = lrec[i];
            int d0 = r0 >> 16, sA = r0 & 0xffff;
            uint4 v0 = *((const uint4*)(xb + (size_t)sA * KDIN + q * 32) + k4);
            float* a0 = acc + d0 * 33 + k4 * 8;
            ADD8(a0, v0);
        }
    }
    __syncthreads();

    // ---- writeout bf16
    if (node < NN) {
        float* ap = acc + tid * 33;
        uint4* orow = (uint4*)(hb + (size_t)node * KDIN + q * 32);
#pragma unroll
        for (int j = 0; j < 4; ++j) {
            uint4 o;
            o.x = (unsigned)f2bf(ap[j * 8 + 0]) | ((unsigned)f2bf(ap[j * 8 + 1]) << 16);
            o.y = (unsigned)f2bf(ap[j * 8 + 2]) | ((unsigned)f2bf(ap[j * 8 + 3]) << 16);
            o.z = (unsigned)f2bf(ap[j * 8 + 4]) | ((unsigned)f2bf(ap[j * 8 + 5]) << 16);
            o.w = (unsigned)f2bf(ap[j * 8 + 6]) | ((unsigned)f2bf(ap[j * 8 + 7]) << 16);
            orow[j] = o;
        }
    }
}

// ------------------------------------------------------------ MFMA GEMMs
// Block: 256 threads = 4 waves. Tile BM=128 x BN=128. Wave w: rows w*32..+31.
// W^T column slice staged in LDS, XOR-swizzled: byte ^= (col&7)<<4.
// A-fragments loaded directly from global (L3-resident, read once per block).

#define STAGE_WT(Wt_, Kc_, K2_)                                                 \
    for (int id = tid; id < BNT * (K2_) / 16; id += 256) {                      \
        int c = id / ((K2_) / 16);                                              \
        int koff = (id % ((K2_) / 16)) * 16;                                    \
        uint4 v = *(const uint4*)((const char*)((Wt_) + (size_t)(ncol0 + c) * (Kc_)) + koff); \
        *(uint4*)((char*)s + c * (K2_) + (koff ^ ((c & 7) << 4))) = v;          \
    }

#define MM_LOOP(A_, Kc_, K2_, acc0_, acc1_)                                     \
    {                                                                           \
        const char* a0p = (const char*)((A_) + (size_t)r0 * (Kc_)) + lq * 16;   \
        const char* a1p = a0p + 16 * (Kc_) * 2;                                 \
        for (int k0 = 0; k0 < (Kc_); k0 += 32) {                                \
            bf16x8 a0 = *(const bf16x8*)(a0p + k0 * 2);                         \
            bf16x8 a1 = *(const bf16x8*)(a1p + k0 * 2);                         \
            int kb = (k0 + lq * 8) * 2;                                         \
            _Pragma("unroll")                                                   \
            for (int nt = 0; nt < 8; ++nt) {                                    \
                int c = nt * 16 + l15;                                          \
                bf16x8 b = *(const bf16x8*)((const char*)s + c * (K2_) + (kb ^ ((c & 7) << 4))); \
                acc0_[nt] = __builtin_amdgcn_mfma_f32_16x16x32_bf16(a0, b, acc0_[nt], 0, 0, 0); \
                acc1_[nt] = __builtin_amdgcn_mfma_f32_16x16x32_bf16(a1, b, acc1_[nt], 0, 0, 0); \
            }                                                                   \
        }                                                                       \
    }

#define BNT 128

// GEMM1: h1 = relu(bn1(h @ W1 + b1))   [NPAD,128]x[128,256] -> bf16 [NPAD,256]
__global__ __launch_bounds__(256) void k_mm1(
    const ushort* __restrict__ A, const ushort* __restrict__ Wt,
    const float* __restrict__ bb, const float* __restrict__ g,
    const float* __restrict__ bt, const float* __restrict__ m,
    const float* __restrict__ vv, ushort* __restrict__ C) {
    __shared__ ushort s[BNT * 128];                  // 32 KB
    int tid = threadIdx.x;
    int bm = blockIdx.x >> 1, bn = blockIdx.x & 1;
    int ncol0 = bn * BNT;
    STAGE_WT(Wt, 128, 256);
    __syncthreads();
    int wid = tid >> 6, lane = tid & 63;
    int l15 = lane & 15, lq = lane >> 4;
    int r0 = bm * 128 + wid * 32 + l15;
    f32x4 acc0[8] = {}, acc1[8] = {};
    MM_LOOP(A, 128, 256, acc0, acc1);
#pragma unroll
    for (int nt = 0; nt < 8; ++nt) {
        int col = ncol0 + nt * 16 + l15;
        float sc = g[col] * rsqrtf(vv[col] + 1e-5f);
        float bo = (bb[col] - m[col]) * sc + bt[col];
        int rb = bm * 128 + wid * 32 + lq * 4;
#pragma unroll
        for (int r = 0; r < 4; ++r) {
            C[(size_t)(rb + r) * KDOUT + col] = f2bf(fmaxf(acc0[nt][r] * sc + bo, 0.f));
            C[(size_t)(rb + 16 + r) * KDOUT + col] = f2bf(fmaxf(acc1[nt][r] * sc + bo, 0.f));
        }
    }
}

// GEMM2 fused: out = relu( relu(bn2(h1 @ W2 + b2)) + x @ Wres )
__global__ __launch_bounds__(256) void k_mm2(
    const ushort* __restrict__ H1, const ushort* __restrict__ W2t,
    const ushort* __restrict__ X, const ushort* __restrict__ Wrt,
    const float* __restrict__ bb, const float* __restrict__ g,
    const float* __restrict__ bt, const float* __restrict__ m,
    const float* __restrict__ vv, float* __restrict__ OUT) {
    __shared__ ushort s[BNT * 256];                  // 64 KB
    int tid = threadIdx.x;
    int bm = blockIdx.x >> 1, bn = blockIdx.x & 1;
    int ncol0 = bn * BNT;
    int wid = tid >> 6, lane = tid & 63;
    int l15 = lane & 15, lq = lane >> 4;
    int r0 = bm * 128 + wid * 32 + l15;

    STAGE_WT(W2t, 256, 512);                         // phase 1: h1 @ W2
    __syncthreads();
    f32x4 acc0[8] = {}, acc1[8] = {};
    MM_LOOP(H1, 256, 512, acc0, acc1);

    __syncthreads();                                 // re-stage: Wres^T
    STAGE_WT(Wrt, 128, 256);
    __syncthreads();
    f32x4 acd0[8] = {}, acd1[8] = {};
    MM_LOOP(X, 128, 256, acd0, acd1);

#pragma unroll
    for (int nt = 0; nt < 8; ++nt) {
        int col = ncol0 + nt * 16 + l15;
        float sc = g[col] * rsqrtf(vv[col] + 1e-5f);
        float bo = (bb[col] - m[col]) * sc + bt[col];
        int rb = bm * 128 + wid * 32 + lq * 4;
#pragma unroll
        for (int r = 0; r < 4; ++r) {
            int row0 = rb + r, row1 = rb + 16 + r;
            float t0 = fmaxf(acc0[nt][r] * sc + bo, 0.f);
            float t1 = fmaxf(acc1[nt][r] * sc + bo, 0.f);
            if (row0 < NN) OUT[(size_t)row0 * KDOUT + col] = fmaxf(t0 + acd0[nt][r], 0.f);
            if (row1 < NN) OUT[(size_t)row1 * KDOUT + col] = fmaxf(t1 + acd1[nt][r], 0.f);
        }
    }
}

// ------------------------------------------------------------------- launch
extern "C" void kernel_launch(void* const* d_in, const int* in_sizes, int n_in,
                              void* d_out, int out_size, void* d_ws, size_t ws_size,
                              hipStream_t stream) {
    const float* x    = (const float*)d_in[0];
    const int*   ei   = (const int*)d_in[1];
    const float* eps  = (const float*)d_in[2];
    const float* W1   = (const float*)d_in[3];
    const float* b1   = (const float*)d_in[4];
    const float* g1   = (const float*)d_in[5];
    const float* bt1  = (const float*)d_in[6];
    const float* m1   = (const float*)d_in[7];
    const float* v1   = (const float*)d_in[8];
    const float* W2   = (const float*)d_in[9];
    const float* b2   = (const float*)d_in[10];
    const float* g2   = (const float*)d_in[11];
    const float* bt2  = (const float*)d_in[12];
    const float* m2   = (const float*)d_in[13];
    const float* v2   = (const float*)d_in[14];
    const float* Wres = (const float*)d_in[15];
    float* out = (float*)d_out;

    char* w = (char*)d_ws;
    ushort* xb  = (ushort*)w;                 w += (size_t)NPAD * KDIN * 2;   // 10.3 MB
    ushort* hb  = (ushort*)w;                 w += (size_t)NPAD * KDIN * 2;   // 10.3 MB
    ushort* h1b = (ushort*)w;                 w += (size_t)NPAD * KDOUT * 2;  // 20.5 MB
    ushort* w1t = (ushort*)w;                 w += 256 * 128 * 2;
    ushort* w2t = (ushort*)w;                 w += 256 * 256 * 2;
    ushort* wrt = (ushort*)w;                 w += 256 * 128 * 2;
    unsigned int* recs = (unsigned int*)w;    w += (size_t)NBIN * 4096 * 4;   // 2.57 MB
    int* lmat   = (int*)w;                    w += (size_t)NBIN * 158 * 4;    // 99 KB

    // front: edge binning || x->bf16 || weight transposes || hb pad zero
    k_front<<<FRONT_GRID, 256, 0, stream>>>(x, W1, W2, Wres, ei, xb, w1t,
                                            recs, lmat, hb);
    // aggregate: per (bucket, dim-quarter), LDS fp32 atomic accumulation
    k_aggC<<<NBIN * 4, 256, 0, stream>>>(recs, lmat, xb, eps, hb);

    const int grid = (NPAD / 128) * 2;        // 313 m-tiles x 2 n-tiles
    k_mm1<<<grid, 256, 0, stream>>>(hb, w1t, b1, g1, bt1, m1, v1, h1b);
    k_mm2<<<grid, 256, 0, stream>>>(h1b, w2t, xb, wrt, b2, g2, bt2, m2, v2, out);
}

// Round 10
// 114.790 us; speedup vs baseline: 5.3424x; 5.3424x over previous
//
#include <hip/hip_runtime.h>

#define NN 40000
#define NPAD 40064          // 313 * 128
#define EE 640000
#define KDIN 128
#define KDOUT 256

#define NBIN 157            // coarse buckets: dst >> 8, and edge chunks of 4096
#define BCAP 5120           // LDS bucket capacity (mean 4076, sigma 64 -> +16 sigma)
#define HCAP 2816           // half-bucket capacity (mean 2038, sigma 45 -> +17 sigma)

typedef __attribute__((ext_vector_type(8))) short bf16x8;   // 8 bf16 = 4 VGPR
typedef __attribute__((ext_vector_type(4))) float f32x4;    // MFMA acc

static __device__ __forceinline__ unsigned short f2bf(float f) {
    union { float f; unsigned int u; } v; v.f = f;
    unsigned int r = (v.u + 0x7FFFu + ((v.u >> 16) & 1u)) >> 16;  // RNE
    return (unsigned short)r;
}
static __device__ __forceinline__ float bf2f(unsigned short h) {
    union { unsigned int u; float f; } v; v.u = ((unsigned int)h) << 16;
    return v.f;
}

// ------------------------------------------------------------------ front
// One kernel, independent block-range jobs (no intra-kernel dependencies):
//   [0, 157)       : edge binning — sort 4096-edge chunk by dst>>8 in LDS,
//                    write sorted recs (coalesced) + per-bucket offsets lmat
//   [157, 2661)    : x -> bf16 (NPAD rows; pad rows = 0)
//   [2661, 3173)   : W1/W2/Wres transpose+convert -> w1t|w2t|wrt (concat)
//   [3173, 3177)   : hb pad rows = 0
// Record: (dst & 255) << 16 | src   (src < 65536)
#define FRONT_GRID 3177
__global__ __launch_bounds__(256) void k_front(
    const float* __restrict__ x,
    const float* __restrict__ W1, const float* __restrict__ W2,
    const float* __restrict__ Wres, const int* __restrict__ ei,
    ushort* __restrict__ xb, ushort* __restrict__ wt_all,
    unsigned int* __restrict__ recs, int* __restrict__ lmat,
    ushort* __restrict__ hb) {
    __shared__ unsigned int SM[4096 + 480 + 256];    // 19.3 KB, binning branch only
    int b = blockIdx.x, tid = threadIdx.x;
    if (b < NBIN) {                                  // ---- edge binning
        unsigned int* lrec = SM;
        int* cnt    = (int*)(SM + 4096);
        int* lstart = cnt + 160;
        int* lcur   = lstart + 160;
        int* sw     = lcur + 160;                    // [256]
        int e0 = b * 4096;
        int ns = min(e0 + 4096, EE) - e0;

        if (tid < NBIN) cnt[tid] = 0;
        __syncthreads();
        for (int s = tid; s < ns; s += 256)
            atomicAdd(&cnt[ei[EE + e0 + s] >> 8], 1);
        __syncthreads();
        sw[tid] = (tid < NBIN) ? cnt[tid] : 0;
        __syncthreads();
        for (int off = 1; off < 256; off <<= 1) {
            int add = (tid >= off) ? sw[tid - off] : 0;
            __syncthreads();
            sw[tid] += add;
            __syncthreads();
        }
        if (tid < NBIN) {
            int st = sw[tid] - cnt[tid];
            lstart[tid] = st;
            lcur[tid] = st;
        }
        __syncthreads();
        for (int s = tid; s < ns; s += 256) {
            int e = e0 + s;
            int src = ei[e];
            int dst = ei[EE + e];
            int p = atomicAdd(&lcur[dst >> 8], 1);
            lrec[p] = ((unsigned int)(dst & 255) << 16) | (unsigned int)src;
        }
        __syncthreads();
        for (int s = tid; s < ns; s += 256)          // coalesced sorted chunk
            recs[b * 4096 + s] = lrec[s];
        if (tid < NBIN + 1)
            lmat[b * 158 + tid] = (tid < NBIN) ? lstart[tid] : ns;
    } else if (b < 2661) {                           // ---- x convert
        int i = (b - NBIN) * 256 + tid;              // elem8 index
        int row = i >> 4;
        uint4 o = {0, 0, 0, 0};
        if (row < NN) {
            const float4* xp = (const float4*)x + (size_t)i * 2;
            float4 a = xp[0], c = xp[1];
            o.x = (unsigned)f2bf(a.x) | ((unsigned)f2bf(a.y) << 16);
            o.y = (unsigned)f2bf(a.z) | ((unsigned)f2bf(a.w) << 16);
            o.z = (unsigned)f2bf(c.x) | ((unsigned)f2bf(c.y) << 16);
            o.w = (unsigned)f2bf(c.z) | ((unsigned)f2bf(c.w) << 16);
        }
        if (row < NPAD) *(uint4*)(xb + (size_t)i * 8) = o;
    } else if (b < 3173) {                           // ---- weight transposes
        int j = (b - 2661) * 256 + tid;              // concat index
        if (j < 32768) {                             // w1t [256][128]
            int c = j >> 7, r = j & 127;
            wt_all[j] = f2bf(W1[r * KDOUT + c]);
        } else if (j < 98304) {                      // w2t [256][256]
            int j2 = j - 32768;
            int c = j2 >> 8, r = j2 & 255;
            wt_all[j] = f2bf(W2[r * KDOUT + c]);
        } else {                                     // wrt [256][128]
            int j3 = j - 98304;
            int c = j3 >> 7, r = j3 & 127;
            wt_all[j] = f2bf(Wres[r * KDOUT + c]);
        }
    } else {                                         // ---- hb pad rows = 0
        int idx = (b - 3173) * 256 + tid;            // 1024 uint4 = 16 KB
        ((uint4*)(hb + (size_t)NN * KDIN))[idx] = (uint4){0, 0, 0, 0};
    }
}

// ----------------------- aggregate: coalesced pack + LDS sort + reg gather
// Grid NBIN*8: blockIdx = b*8 + nh*4 + q  (nh: node-half of 128 nodes,
// q: dim-quarter of 32 dims).
// 1) wave-per-chunk coalesced pack of bucket b into lrec (round-9's pack)
// 2) LDS counting-sort of this half's records by dst low-7 (round-6's sort)
// 3) register gather, 64 groups x 4 lanes, 2 node-iterations.
__global__ __launch_bounds__(256) void k_aggD(
    const unsigned int* __restrict__ recs, const int* __restrict__ lmat,
    const ushort* __restrict__ xb, const float* __restrict__ eps,
    ushort* __restrict__ hb) {
    __shared__ unsigned int lrec[BCAP];              // 20 KB
    __shared__ ushort lsrc[HCAP];                    // 5.5 KB
    __shared__ int lcnt[128], lst[128], lcur[128];
    __shared__ int sw[256];
    int tid = threadIdx.x;
    int bi = blockIdx.x;
    int b = bi >> 3, nh = (bi >> 2) & 1, q = bi & 3;
    int wid = tid >> 6, lane = tid & 63;

    // ---- segment-length scan (chunk-order prefix for pack offsets)
    int len0 = 0;
    if (tid < NBIN) len0 = lmat[tid * 158 + b + 1] - lmat[tid * 158 + b];
    sw[tid] = len0;
    __syncthreads();
    for (int off = 1; off < 256; off <<= 1) {
        int add = (tid >= off) ? sw[tid - off] : 0;
        __syncthreads();
        sw[tid] += add;
        __syncthreads();
    }
    int ctot = sw[255];

    // ---- coalesced pack: one wave per chunk, lanes along the segment
    for (int c = wid; c < NBIN; c += 4) {
        int s0 = lmat[c * 158 + b];
        int len = lmat[c * 158 + b + 1] - s0;
        int pofs = sw[c] - len;                      // exclusive prefix
        const unsigned int* seg = recs + c * 4096 + s0;
        for (int i = lane; i < len; i += 64)
            lrec[pofs + i] = seg[i];
    }
    if (tid < 128) lcnt[tid] = 0;
    __syncthreads();

    // ---- counting-sort this node-half by dst low-7
    for (int s = tid; s < ctot; s += 256) {
        int d8 = lrec[s] >> 16;
        if ((d8 >> 7) == nh) atomicAdd(&lcnt[d8 & 127], 1);
    }
    __syncthreads();
    sw[tid] = (tid < 128) ? lcnt[tid] : 0;
    __syncthreads();
    for (int off = 1; off < 128; off <<= 1) {
        int add = (tid >= off) ? sw[tid - off] : 0;
        __syncthreads();
        sw[tid] += add;
        __syncthreads();
    }
    if (tid < 128) {
        int e = sw[tid] - lcnt[tid];
        lst[tid] = e;
        lcur[tid] = e;
    }
    __syncthreads();
    for (int s = tid; s < ctot; s += 256) {
        unsigned int r = lrec[s];
        int d8 = r >> 16;
        if ((d8 >> 7) == nh) {
            int p = atomicAdd(&lcur[d8 & 127], 1);
            lsrc[p] = (ushort)(r & 0xffff);
        }
    }
    __syncthreads();

    // ---- gather: 64 groups x 4 lanes; group g -> nodes {g, g+64}
    int g = tid >> 2, lane4 = tid & 3;
    float s1 = 1.0f + eps[0];
    for (int it = 0; it < 2; ++it) {
        int d = g + it * 64;
        int node = b * 256 + nh * 128 + d;
        if (node >= NN) continue;
        int st = lst[d], en = st + lcnt[d];
        uint4 me = *((const uint4*)(xb + (size_t)node * KDIN) + q * 4 + lane4);
        float a[8], a2[8];
        a[0] = bf2f((ushort)(me.x & 0xffff)) * s1; a[1] = bf2f((ushort)(me.x >> 16)) * s1;
        a[2] = bf2f((ushort)(me.y & 0xffff)) * s1; a[3] = bf2f((ushort)(me.y >> 16)) * s1;
        a[4] = bf2f((ushort)(me.z & 0xffff)) * s1; a[5] = bf2f((ushort)(me.z >> 16)) * s1;
        a[6] = bf2f((ushort)(me.w & 0xffff)) * s1; a[7] = bf2f((ushort)(me.w >> 16)) * s1;
#pragma unroll
        for (int i = 0; i < 8; ++i) a2[i] = 0.f;
        int e = st;
        for (; e + 1 < en; e += 2) {                 // 2 loads in flight
            int sA = lsrc[e], sB = lsrc[e + 1];
            uint4 v0 = *((const uint4*)(xb + (size_t)sA * KDIN) + q * 4 + lane4);
            uint4 v1 = *((const uint4*)(xb + (size_t)sB * KDIN) + q * 4 + lane4);
            a[0] += bf2f((ushort)(v0.x & 0xffff)); a[1] += bf2f((ushort)(v0.x >> 16));
            a[2] += bf2f((ushort)(v0.y & 0xffff)); a[3] += bf2f((ushort)(v0.y >> 16));
            a[4] += bf2f((ushort)(v0.z & 0xffff)); a[5] += bf2f((ushort)(v0.z >> 16));
            a[6] += bf2f((ushort)(v0.w & 0xffff)); a[7] += bf2f((ushort)(v0.w >> 16));
            a2[0] += bf2f((ushort)(v1.x & 0xffff)); a2[1] += bf2f((ushort)(v1.x >> 16));
            a2[2] += bf2f((ushort)(v1.y & 0xffff)); a2[3] += bf2f((ushort)(v1.y >> 16));
            a2[4] += bf2f((ushort)(v1.z & 0xffff)); a2[5] += bf2f((ushort)(v1.z >> 16));
            a2[6] += bf2f((ushort)(v1.w & 0xffff)); a2[7] += bf2f((ushort)(v1.w >> 16));
        }
        if (e < en) {
            int sA = lsrc[e];
            uint4 v0 = *((const uint4*)(xb + (size_t)sA * KDIN) + q * 4 + lane4);
            a[0] += bf2f((ushort)(v0.x & 0xffff)); a[1] += bf2f((ushort)(v0.x >> 16));
            a[2] += bf2f((ushort)(v0.y & 0xffff)); a[3] += bf2f((ushort)(v0.y >> 16));
            a[4] += bf2f((ushort)(v0.z & 0xffff)); a[5] += bf2f((ushort)(v0.z >> 16));
            a[6] += bf2f((ushort)(v0.w & 0xffff)); a[7] += bf2f((ushort)(v0.w >> 16));
        }
#pragma unroll
        for (int i = 0; i < 8; ++i) a[i] += a2[i];
        uint4 o;
        o.x = (unsigned)f2bf(a[0]) | ((unsigned)f2bf(a[1]) << 16);
        o.y = (unsigned)f2bf(a[2]) | ((unsigned)f2bf(a[3]) << 16);
        o.z = (unsigned)f2bf(a[4]) | ((unsigned)f2bf(a[5]) << 16);
        o.w = (unsigned)f2bf(a[6]) | ((unsigned)f2bf(a[7]) << 16);
        *((uint4*)(hb + (size_t)node * KDIN) + q * 4 + lane4) = o;
    }
}

// ------------------------------------------------------------ MFMA GEMMs
// Block: 256 threads = 4 waves. Tile BM=128 x BN=128. Wave w: rows w*32..+31.
// W^T column slice staged in LDS, XOR-swizzled: byte ^= (col&7)<<4.
// A-fragments loaded directly from global (L3-resident, read once per block).

#define STAGE_WT(Wt_, Kc_, K2_)                                                 \
    for (int id = tid; id < BNT * (K2_) / 16; id += 256) {                      \
        int c = id / ((K2_) / 16);                                              \
        int koff = (id % ((K2_) / 16)) * 16;                                    \
        uint4 v = *(const uint4*)((const char*)((Wt_) + (size_t)(ncol0 + c) * (Kc_)) + koff); \
        *(uint4*)((char*)s + c * (K2_) + (koff ^ ((c & 7) << 4))) = v;          \
    }

#define MM_LOOP(A_, Kc_, K2_, acc0_, acc1_)                                     \
    {                                                                           \
        const char* a0p = (const char*)((A_) + (size_t)r0 * (Kc_)) + lq * 16;   \
        const char* a1p = a0p + 16 * (Kc_) * 2;                                 \
        for (int k0 = 0; k0 < (Kc_); k0 += 32) {                                \
            bf16x8 a0 = *(const bf16x8*)(a0p + k0 * 2);                         \
            bf16x8 a1 = *(const bf16x8*)(a1p + k0 * 2);                         \
            int kb = (k0 + lq * 8) * 2;                                         \
            _Pragma("unroll")                                                   \
            for (int nt = 0; nt < 8; ++nt) {                                    \
                int c = nt * 16 + l15;                                          \
                bf16x8 b = *(const bf16x8*)((const char*)s + c * (K2_) + (kb ^ ((c & 7) << 4))); \
                acc0_[nt] = __builtin_amdgcn_mfma_f32_16x16x32_bf16(a0, b, acc0_[nt], 0, 0, 0); \
                acc1_[nt] = __builtin_amdgcn_mfma_f32_16x16x32_bf16(a1, b, acc1_[nt], 0, 0, 0); \
            }                                                                   \
        }                                                                       \
    }

#define BNT 128

// GEMM1: h1 = relu(bn1(h @ W1 + b1))   [NPAD,128]x[128,256] -> bf16 [NPAD,256]
__global__ __launch_bounds__(256) void k_mm1(
    const ushort* __restrict__ A, const ushort* __restrict__ Wt,
    const float* __restrict__ bb, const float* __restrict__ g,
    const float* __restrict__ bt, const float* __restrict__ m,
    const float* __restrict__ vv, ushort* __restrict__ C) {
    __shared__ ushort s[BNT * 128];                  // 32 KB
    int tid = threadIdx.x;
    int bm = blockIdx.x >> 1, bn = blockIdx.x & 1;
    int ncol0 = bn * BNT;
    STAGE_WT(Wt, 128, 256);
    __syncthreads();
    int wid = tid >> 6, lane = tid & 63;
    int l15 = lane & 15, lq = lane >> 4;
    int r0 = bm * 128 + wid * 32 + l15;
    f32x4 acc0[8] = {}, acc1[8] = {};
    MM_LOOP(A, 128, 256, acc0, acc1);
#pragma unroll
    for (int nt = 0; nt < 8; ++nt) {
        int col = ncol0 + nt * 16 + l15;
        float sc = g[col] * rsqrtf(vv[col] + 1e-5f);
        float bo = (bb[col] - m[col]) * sc + bt[col];
        int rb = bm * 128 + wid * 32 + lq * 4;
#pragma unroll
        for (int r = 0; r < 4; ++r) {
            C[(size_t)(rb + r) * KDOUT + col] = f2bf(fmaxf(acc0[nt][r] * sc + bo, 0.f));
            C[(size_t)(rb + 16 + r) * KDOUT + col] = f2bf(fmaxf(acc1[nt][r] * sc + bo, 0.f));
        }
    }
}

// GEMM2 fused: out = relu( relu(bn2(h1 @ W2 + b2)) + x @ Wres )
__global__ __launch_bounds__(256) void k_mm2(
    const ushort* __restrict__ H1, const ushort* __restrict__ W2t,
    const ushort* __restrict__ X, const ushort* __restrict__ Wrt,
    const float* __restrict__ bb, const float* __restrict__ g,
    const float* __restrict__ bt, const float* __restrict__ m,
    const float* __restrict__ vv, float* __restrict__ OUT) {
    __shared__ ushort s[BNT * 256];                  // 64 KB
    int tid = threadIdx.x;
    int bm = blockIdx.x >> 1, bn = blockIdx.x & 1;
    int ncol0 = bn * BNT;
    int wid = tid >> 6, lane = tid & 63;
    int l15 = lane & 15, lq = lane >> 4;
    int r0 = bm * 128 + wid * 32 + l15;

    STAGE_WT(W2t, 256, 512);                         // phase 1: h1 @ W2
    __syncthreads();
    f32x4 acc0[8] = {}, acc1[8] = {};
    MM_LOOP(H1, 256, 512, acc0, acc1);

    __syncthreads();                                 // re-stage: Wres^T
    STAGE_WT(Wrt, 128, 256);
    __syncthreads();
    f32x4 acd0[8] = {}, acd1[8] = {};
    MM_LOOP(X, 128, 256, acd0, acd1);

#pragma unroll
    for (int nt = 0; nt < 8; ++nt) {
        int col = ncol0 + nt * 16 + l15;
        float sc = g[col] * rsqrtf(vv[col] + 1e-5f);
        float bo = (bb[col] - m[col]) * sc + bt[col];
        int rb = bm * 128 + wid * 32 + lq * 4;
#pragma unroll
        for (int r = 0; r < 4; ++r) {
            int row0 = rb + r, row1 = rb + 16 + r;
            float t0 = fmaxf(acc0[nt][r] * sc + bo, 0.f);
            float t1 = fmaxf(acc1[nt][r] * sc + bo, 0.f);
            if (row0 < NN) OUT[(size_t)row0 * KDOUT + col] = fmaxf(t0 + acd0[nt][r], 0.f);
            if (row1 < NN) OUT[(size_t)row1 * KDOUT + col] = fmaxf(t1 + acd1[nt][r], 0.f);
        }
    }
}

// ------------------------------------------------------------------- launch
extern "C" void kernel_launch(void* const* d_in, const int* in_sizes, int n_in,
                              void* d_out, int out_size, void* d_ws, size_t ws_size,
                              hipStream_t stream) {
    const float* x    = (const float*)d_in[0];
    const int*   ei   = (const int*)d_in[1];
    const float* eps  = (const float*)d_in[2];
    const float* W1   = (const float*)d_in[3];
    const float* b1   = (const float*)d_in[4];
    const float* g1   = (const float*)d_in[5];
    const float* bt1  = (const float*)d_in[6];
    const float* m1   = (const float*)d_in[7];
    const float* v1   = (const float*)d_in[8];
    const float* W2   = (const float*)d_in[9];
    const float* b2   = (const float*)d_in[10];
    const float* g2   = (const float*)d_in[11];
    const float* bt2  = (const float*)d_in[12];
    const float* m2   = (const float*)d_in[13];
    const float* v2   = (const float*)d_in[14];
    const float* Wres = (const float*)d_in[15];
    float* out = (float*)d_out;

    char* w = (char*)d_ws;
    ushort* xb  = (ushort*)w;                 w += (size_t)NPAD * KDIN * 2;   // 10.3 MB
    ushort* hb  = (ushort*)w;                 w += (size_t)NPAD * KDIN * 2;   // 10.3 MB
    ushort* h1b = (ushort*)w;                 w += (size_t)NPAD * KDOUT * 2;  // 20.5 MB
    ushort* w1t = (ushort*)w;                 w += 256 * 128 * 2;
    ushort* w2t = (ushort*)w;                 w += 256 * 256 * 2;
    ushort* wrt = (ushort*)w;                 w += 256 * 128 * 2;
    unsigned int* recs = (unsigned int*)w;    w += (size_t)NBIN * 4096 * 4;   // 2.57 MB
    int* lmat   = (int*)w;                    w += (size_t)NBIN * 158 * 4;    // 99 KB

    // front: edge binning || x->bf16 || weight transposes || hb pad zero
    k_front<<<FRONT_GRID, 256, 0, stream>>>(x, W1, W2, Wres, ei, xb, w1t,
                                            recs, lmat, hb);
    // aggregate: per (bucket, node-half, dim-quarter) — pack + sort + gather
    k_aggD<<<NBIN * 8, 256, 0, stream>>>(recs, lmat, xb, eps, hb);

    const int grid = (NPAD / 128) * 2;        // 313 m-tiles x 2 n-tiles
    k_mm1<<<grid, 256, 0, stream>>>(hb, w1t, b1, g1, bt1, m1, v1, h1b);
    k_mm2<<<grid, 256, 0, stream>>>(h1b, w2t, xb, wrt, b2, g2, bt2, m2, v2, out);
}

// Round 13
// 109.814 us; speedup vs baseline: 5.5845x; 1.0453x over previous
//
#include <hip/hip_runtime.h>

#define NN 40000
#define NPAD 40192          // 157 * 256
#define EE 640000
#define KDIN 128
#define KDOUT 256

#define NBIN 157            // coarse buckets: dst >> 8, and edge chunks of 4096
#define BCAP 5120           // LDS bucket capacity (mean 4076, sigma 64 -> +16 sigma)
#define HCAP 2816           // half-bucket capacity (mean 2038, sigma 45 -> +17 sigma)

typedef __attribute__((ext_vector_type(8))) short bf16x8;   // 8 bf16 = 4 VGPR
typedef __attribute__((ext_vector_type(4))) float f32x4;    // MFMA acc

static __device__ __forceinline__ unsigned short f2bf(float f) {
    union { float f; unsigned int u; } v; v.f = f;
    unsigned int r = (v.u + 0x7FFFu + ((v.u >> 16) & 1u)) >> 16;  // RNE
    return (unsigned short)r;
}
static __device__ __forceinline__ float bf2f(unsigned short h) {
    union { unsigned int u; float f; } v; v.u = ((unsigned int)h) << 16;
    return v.f;
}

// ------------------------------------------------------------------ front
// One kernel, independent block-range jobs (no intra-kernel dependencies):
//   [0, 157)       : edge binning — sort 4096-edge chunk by dst>>8 in LDS,
//                    write sorted recs (coalesced) + per-bucket offsets lmat
//   [157, 2669)    : x -> bf16 (NPAD rows; pad rows = 0)
//   [2669, 3181)   : W1/W2/Wres transpose+convert -> w1t|w2t|wrt (concat)
//   [3181, 3193)   : hb pad rows = 0 (192 rows)
// Record: (dst & 255) << 16 | src   (src < 65536)
#define FRONT_GRID 3193
__global__ __launch_bounds__(256) void k_front(
    const float* __restrict__ x,
    const float* __restrict__ W1, const float* __restrict__ W2,
    const float* __restrict__ Wres, const int* __restrict__ ei,
    ushort* __restrict__ xb, ushort* __restrict__ wt_all,
    unsigned int* __restrict__ recs, int* __restrict__ lmat,
    ushort* __restrict__ hb) {
    __shared__ unsigned int SM[4096 + 480 + 256];    // 19.3 KB, binning branch only
    int b = blockIdx.x, tid = threadIdx.x;
    if (b < NBIN) {                                  // ---- edge binning
        unsigned int* lrec = SM;
        int* cnt    = (int*)(SM + 4096);
        int* lstart = cnt + 160;
        int* lcur   = lstart + 160;
        int* sw     = lcur + 160;                    // [256]
        int e0 = b * 4096;
        int ns = min(e0 + 4096, EE) - e0;

        if (tid < NBIN) cnt[tid] = 0;
        __syncthreads();
        for (int s = tid; s < ns; s += 256)
            atomicAdd(&cnt[ei[EE + e0 + s] >> 8], 1);
        __syncthreads();
        sw[tid] = (tid < NBIN) ? cnt[tid] : 0;
        __syncthreads();
        for (int off = 1; off < 256; off <<= 1) {
            int add = (tid >= off) ? sw[tid - off] : 0;
            __syncthreads();
            sw[tid] += add;
            __syncthreads();
        }
        if (tid < NBIN) {
            int st = sw[tid] - cnt[tid];
            lstart[tid] = st;
            lcur[tid] = st;
        }
        __syncthreads();
        for (int s = tid; s < ns; s += 256) {
            int e = e0 + s;
            int src = ei[e];
            int dst = ei[EE + e];
            int p = atomicAdd(&lcur[dst >> 8], 1);
            lrec[p] = ((unsigned int)(dst & 255) << 16) | (unsigned int)src;
        }
        __syncthreads();
        for (int s = tid; s < ns; s += 256)          // coalesced sorted chunk
            recs[b * 4096 + s] = lrec[s];
        if (tid < NBIN + 1)
            lmat[b * 158 + tid] = (tid < NBIN) ? lstart[tid] : ns;
    } else if (b < 2669) {                           // ---- x convert
        int i = (b - NBIN) * 256 + tid;              // elem8 index
        int row = i >> 4;
        uint4 o = {0, 0, 0, 0};
        if (row < NN) {
            const float4* xp = (const float4*)x + (size_t)i * 2;
            float4 a = xp[0], c = xp[1];
            o.x = (unsigned)f2bf(a.x) | ((unsigned)f2bf(a.y) << 16);
            o.y = (unsigned)f2bf(a.z) | ((unsigned)f2bf(a.w) << 16);
            o.z = (unsigned)f2bf(c.x) | ((unsigned)f2bf(c.y) << 16);
            o.w = (unsigned)f2bf(c.z) | ((unsigned)f2bf(c.w) << 16);
        }
        *(uint4*)(xb + (size_t)i * 8) = o;           // i < NPAD*16 by grid
    } else if (b < 3181) {                           // ---- weight transposes
        int j = (b - 2669) * 256 + tid;              // concat index
        if (j < 32768) {                             // w1t [256][128]
            int c = j >> 7, r = j & 127;
            wt_all[j] = f2bf(W1[r * KDOUT + c]);
        } else if (j < 98304) {                      // w2t [256][256]
            int j2 = j - 32768;
            int c = j2 >> 8, r = j2 & 255;
            wt_all[j] = f2bf(W2[r * KDOUT + c]);
        } else {                                     // wrt [256][128]
            int j3 = j - 98304;
            int c = j3 >> 7, r = j3 & 127;
            wt_all[j] = f2bf(Wres[r * KDOUT + c]);
        }
    } else {                                         // ---- hb pad rows = 0
        int idx = (b - 3181) * 256 + tid;            // 3072 uint4 = 48 KB
        ((uint4*)(hb + (size_t)NN * KDIN))[idx] = (uint4){0, 0, 0, 0};
    }
}

// ----------------------- aggregate: coalesced pack + LDS sort + reg gather
// Grid NBIN*8: blockIdx = b*8 + nh*4 + q  (nh: node-half of 128 nodes,
// q: dim-quarter of 32 dims). Gather issues 4 independent loads per step.
// NOTE addressing: xb rows are 128 ushort = 16 uint4 — always offset the
// ushort pointer by node*KDIN first, then index uint4s (round-11 bug: *32).
#define ACC8(arr_, v_)                                                          \
    arr_[0] += bf2f((ushort)((v_).x & 0xffff)); arr_[1] += bf2f((ushort)((v_).x >> 16)); \
    arr_[2] += bf2f((ushort)((v_).y & 0xffff)); arr_[3] += bf2f((ushort)((v_).y >> 16)); \
    arr_[4] += bf2f((ushort)((v_).z & 0xffff)); arr_[5] += bf2f((ushort)((v_).z >> 16)); \
    arr_[6] += bf2f((ushort)((v_).w & 0xffff)); arr_[7] += bf2f((ushort)((v_).w >> 16));

#define XROW(n_) (*((const uint4*)(xb + (size_t)(n_) * KDIN) + qoff))

__global__ __launch_bounds__(256) void k_aggD(
    const unsigned int* __restrict__ recs, const int* __restrict__ lmat,
    const ushort* __restrict__ xb, const float* __restrict__ eps,
    ushort* __restrict__ hb) {
    __shared__ unsigned int lrec[BCAP];              // 20 KB
    __shared__ ushort lsrc[HCAP];                    // 5.5 KB
    __shared__ int lcnt[128], lst[128], lcur[128];
    __shared__ int sw[256];
    int tid = threadIdx.x;
    int bi = blockIdx.x;
    int b = bi >> 3, nh = (bi >> 2) & 1, q = bi & 3;
    int wid = tid >> 6, lane = tid & 63;

    // ---- segment-length scan (chunk-order prefix for pack offsets)
    int len0 = 0;
    if (tid < NBIN) len0 = lmat[tid * 158 + b + 1] - lmat[tid * 158 + b];
    sw[tid] = len0;
    __syncthreads();
    for (int off = 1; off < 256; off <<= 1) {
        int add = (tid >= off) ? sw[tid - off] : 0;
        __syncthreads();
        sw[tid] += add;
        __syncthreads();
    }
    int ctot = sw[255];

    // ---- coalesced pack: one wave per chunk, lanes along the segment
    for (int c = wid; c < NBIN; c += 4) {
        int s0 = lmat[c * 158 + b];
        int len = lmat[c * 158 + b + 1] - s0;
        int pofs = sw[c] - len;                      // exclusive prefix
        const unsigned int* seg = recs + c * 4096 + s0;
        for (int i = lane; i < len; i += 64)
            lrec[pofs + i] = seg[i];
    }
    if (tid < 128) lcnt[tid] = 0;
    __syncthreads();

    // ---- counting-sort this node-half by dst low-7
    for (int s = tid; s < ctot; s += 256) {
        int d8 = lrec[s] >> 16;
        if ((d8 >> 7) == nh) atomicAdd(&lcnt[d8 & 127], 1);
    }
    __syncthreads();
    sw[tid] = (tid < 128) ? lcnt[tid] : 0;
    __syncthreads();
    for (int off = 1; off < 128; off <<= 1) {
        int add = (tid >= off) ? sw[tid - off] : 0;
        __syncthreads();
        sw[tid] += add;
        __syncthreads();
    }
    if (tid < 128) {
        int e = sw[tid] - lcnt[tid];
        lst[tid] = e;
        lcur[tid] = e;
    }
    __syncthreads();
    for (int s = tid; s < ctot; s += 256) {
        unsigned int r = lrec[s];
        int d8 = r >> 16;
        if ((d8 >> 7) == nh) {
            int p = atomicAdd(&lcur[d8 & 127], 1);
            lsrc[p] = (ushort)(r & 0xffff);
        }
    }
    __syncthreads();

    // ---- gather: 64 groups x 4 lanes; group g -> nodes {g, g+64}
    int g = tid >> 2, lane4 = tid & 3;
    int qoff = q * 4 + lane4;                        // uint4 index within row
    float s1 = 1.0f + eps[0];
    for (int it = 0; it < 2; ++it) {
        int d = g + it * 64;
        int node = b * 256 + nh * 128 + d;
        if (node >= NN) continue;
        int st = lst[d], en = st + lcnt[d];
        uint4 me = XROW(node);
        float a[8], a2[8];
#pragma unroll
        for (int i = 0; i < 8; ++i) a2[i] = 0.f;     // ACC8 accumulates: must init
        ACC8(a2, me);                                 // a2 = x[node]
#pragma unroll
        for (int i = 0; i < 8; ++i) { a[i] = a2[i] * s1; a2[i] = 0.f; }
        int e = st;
        for (; e + 3 < en; e += 4) {                 // 4 loads in flight
            int sA = lsrc[e], sB = lsrc[e + 1], sC = lsrc[e + 2], sD = lsrc[e + 3];
            uint4 v0 = XROW(sA);
            uint4 v1 = XROW(sB);
            uint4 v2 = XROW(sC);
            uint4 v3 = XROW(sD);
            ACC8(a, v0);
            ACC8(a2, v1);
            ACC8(a, v2);
            ACC8(a2, v3);
        }
        for (; e < en; ++e) {
            uint4 v0 = XROW(lsrc[e]);
            ACC8(a, v0);
        }
#pragma unroll
        for (int i = 0; i < 8; ++i) a[i] += a2[i];
        uint4 o;
        o.x = (unsigned)f2bf(a[0]) | ((unsigned)f2bf(a[1]) << 16);
        o.y = (unsigned)f2bf(a[2]) | ((unsigned)f2bf(a[3]) << 16);
        o.z = (unsigned)f2bf(a[4]) | ((unsigned)f2bf(a[5]) << 16);
        o.w = (unsigned)f2bf(a[6]) | ((unsigned)f2bf(a[7]) << 16);
        *((uint4*)(hb + (size_t)node * KDIN) + qoff) = o;
    }
}

// ------------------------------------------------------------ MFMA GEMMs
// W^T column slice staged in LDS, XOR-swizzled: byte ^= (col&7)<<4.
// A-fragments loaded directly from global (L3-resident, read once per block).

#define STAGE_WT(Wt_, Kc_, K2_, TPB_)                                           \
    for (int id = tid; id < BNT * (K2_) / 16; id += (TPB_)) {                   \
        int c = id / ((K2_) / 16);                                              \
        int koff = (id % ((K2_) / 16)) * 16;                                    \
        uint4 v = *(const uint4*)((const char*)((Wt_) + (size_t)(ncol0 + c) * (Kc_)) + koff); \
        *(uint4*)((char*)s + c * (K2_) + (koff ^ ((c & 7) << 4))) = v;          \
    }

#define MM_LOOP(A_, Kc_, K2_, acc0_, acc1_)                                     \
    {                                                                           \
        const char* a0p = (const char*)((A_) + (size_t)r0 * (Kc_)) + lq * 16;   \
        const char* a1p = a0p + 16 * (Kc_) * 2;                                 \
        for (int k0 = 0; k0 < (Kc_); k0 += 32) {                                \
            bf16x8 a0 = *(const bf16x8*)(a0p + k0 * 2);                         \
            bf16x8 a1 = *(const bf16x8*)(a1p + k0 * 2);                         \
            int kb = (k0 + lq * 8) * 2;                                         \
            _Pragma("unroll")                                                   \
            for (int nt = 0; nt < 8; ++nt) {                                    \
                int c = nt * 16 + l15;                                          \
                bf16x8 b = *(const bf16x8*)((const char*)s + c * (K2_) + (kb ^ ((c & 7) << 4))); \
                acc0_[nt] = __builtin_amdgcn_mfma_f32_16x16x32_bf16(a0, b, acc0_[nt], 0, 0, 0); \
                acc1_[nt] = __builtin_amdgcn_mfma_f32_16x16x32_bf16(a1, b, acc1_[nt], 0, 0, 0); \
            }                                                                   \
        }                                                                       \
    }

#define BNT 128

// GEMM1: h1 = relu(bn1(h @ W1 + b1))   [NPAD,128]x[128,256] -> bf16 [NPAD,256]
// 256 threads = 4 waves, BM=128, grid (NPAD/128)*2.
__global__ __launch_bounds__(256) void k_mm1(
    const ushort* __restrict__ A, const ushort* __restrict__ Wt,
    const float* __restrict__ bb, const float* __restrict__ g,
    const float* __restrict__ bt, const float* __restrict__ m,
    const float* __restrict__ vv, ushort* __restrict__ C) {
    __shared__ ushort s[BNT * 128];                  // 32 KB
    int tid = threadIdx.x;
    int bm = blockIdx.x >> 1, bn = blockIdx.x & 1;
    int ncol0 = bn * BNT;
    STAGE_WT(Wt, 128, 256, 256);
    __syncthreads();
    int wid = tid >> 6, lane = tid & 63;
    int l15 = lane & 15, lq = lane >> 4;
    int r0 = bm * 128 + wid * 32 + l15;
    f32x4 acc0[8] = {}, acc1[8] = {};
    MM_LOOP(A, 128, 256, acc0, acc1);
#pragma unroll
    for (int nt = 0; nt < 8; ++nt) {
        int col = ncol0 + nt * 16 + l15;
        float sc = g[col] * rsqrtf(vv[col] + 1e-5f);
        float bo = (bb[col] - m[col]) * sc + bt[col];
        int rb = bm * 128 + wid * 32 + lq * 4;
#pragma unroll
        for (int r = 0; r < 4; ++r) {
            C[(size_t)(rb + r) * KDOUT + col] = f2bf(fmaxf(acc0[nt][r] * sc + bo, 0.f));
            C[(size_t)(rb + 16 + r) * KDOUT + col] = f2bf(fmaxf(acc1[nt][r] * sc + bo, 0.f));
        }
    }
}

// GEMM2 fused: out = relu( relu(bn2(h1 @ W2 + b2)) + x @ Wres )
// 512 threads = 8 waves, BM=256 (same 64 KB LDS -> 16 waves/CU vs 8 before).
__global__ __launch_bounds__(512) void k_mm2(
    const ushort* __restrict__ H1, const ushort* __restrict__ W2t,
    const ushort* __restrict__ X, const ushort* __restrict__ Wrt,
    const float* __restrict__ bb, const float* __restrict__ g,
    const float* __restrict__ bt, const float* __restrict__ m,
    const float* __restrict__ vv, float* __restrict__ OUT) {
    __shared__ ushort s[BNT * 256];                  // 64 KB
    int tid = threadIdx.x;
    int bm = blockIdx.x >> 1, bn = blockIdx.x & 1;
    int ncol0 = bn * BNT;
    int wid = tid >> 6, lane = tid & 63;             // wid in [0,8)
    int l15 = lane & 15, lq = lane >> 4;
    int r0 = bm * 256 + wid * 32 + l15;

    STAGE_WT(W2t, 256, 512, 512);                    // phase 1: h1 @ W2
    __syncthreads();
    f32x4 acc0[8] = {}, acc1[8] = {};
    MM_LOOP(H1, 256, 512, acc0, acc1);

    __syncthreads();                                 // re-stage: Wres^T
    STAGE_WT(Wrt, 128, 256, 512);
    __syncthreads();
    f32x4 acd0[8] = {}, acd1[8] = {};
    MM_LOOP(X, 128, 256, acd0, acd1);

#pragma unroll
    for (int nt = 0; nt < 8; ++nt) {
        int col = ncol0 + nt * 16 + l15;
        float sc = g[col] * rsqrtf(vv[col] + 1e-5f);
        float bo = (bb[col] - m[col]) * sc + bt[col];
        int rb = bm * 256 + wid * 32 + lq * 4;
#pragma unroll
        for (int r = 0; r < 4; ++r) {
            int row0 = rb + r, row1 = rb + 16 + r;
            float t0 = fmaxf(acc0[nt][r] * sc + bo, 0.f);
            float t1 = fmaxf(acc1[nt][r] * sc + bo, 0.f);
            if (row0 < NN) OUT[(size_t)row0 * KDOUT + col] = fmaxf(t0 + acd0[nt][r], 0.f);
            if (row1 < NN) OUT[(size_t)row1 * KDOUT + col] = fmaxf(t1 + acd1[nt][r], 0.f);
        }
    }
}

// ------------------------------------------------------------------- launch
extern "C" void kernel_launch(void* const* d_in, const int* in_sizes, int n_in,
                              void* d_out, int out_size, void* d_ws, size_t ws_size,
                              hipStream_t stream) {
    const float* x    = (const float*)d_in[0];
    const int*   ei   = (const int*)d_in[1];
    const float* eps  = (const float*)d_in[2];
    const float* W1   = (const float*)d_in[3];
    const float* b1   = (const float*)d_in[4];
    const float* g1   = (const float*)d_in[5];
    const float* bt1  = (const float*)d_in[6];
    const float* m1   = (const float*)d_in[7];
    const float* v1   = (const float*)d_in[8];
    const float* W2   = (const float*)d_in[9];
    const float* b2   = (const float*)d_in[10];
    const float* g2   = (const float*)d_in[11];
    const float* bt2  = (const float*)d_in[12];
    const float* m2   = (const float*)d_in[13];
    const float* v2   = (const float*)d_in[14];
    const float* Wres = (const float*)d_in[15];
    float* out = (float*)d_out;

    char* w = (char*)d_ws;
    ushort* xb  = (ushort*)w;                 w += (size_t)NPAD * KDIN * 2;   // 10.3 MB
    ushort* hb  = (ushort*)w;                 w += (size_t)NPAD * KDIN * 2;   // 10.3 MB
    ushort* h1b = (ushort*)w;                 w += (size_t)NPAD * KDOUT * 2;  // 20.6 MB
    ushort* w1t = (ushort*)w;                 w += 256 * 128 * 2;
    ushort* w2t = (ushort*)w;                 w += 256 * 256 * 2;
    ushort* wrt = (ushort*)w;                 w += 256 * 128 * 2;
    unsigned int* recs = (unsigned int*)w;    w += (size_t)NBIN * 4096 * 4;   // 2.57 MB
    int* lmat   = (int*)w;                    w += (size_t)NBIN * 158 * 4;    // 99 KB

    // front: edge binning || x->bf16 || weight transposes || hb pad zero
    k_front<<<FRONT_GRID, 256, 0, stream>>>(x, W1, W2, Wres, ei, xb, w1t,
                                            recs, lmat, hb);
    // aggregate: per (bucket, node-half, dim-quarter) — pack + sort + gather
    k_aggD<<<NBIN * 8, 256, 0, stream>>>(recs, lmat, xb, eps, hb);

    k_mm1<<<(NPAD / 128) * 2, 256, 0, stream>>>(hb, w1t, b1, g1, bt1, m1, v1, h1b);
    k_mm2<<<(NPAD / 256) * 2, 512, 0, stream>>>(h1b, w2t, xb, wrt, b2, g2, bt2,
                                                m2, v2, out);
}

// Round 14
// 106.029 us; speedup vs baseline: 5.7838x; 1.0357x over previous
//
#include <hip/hip_runtime.h>

#define NN 40000
#define NPAD 40192          // 157 * 256
#define EE 640000
#define KDIN 128
#define KDOUT 256

#define NBIN 157            // coarse buckets: dst >> 8, and edge chunks of 4096
#define BCAP 5120           // LDS bucket capacity (mean 4076, sigma 64 -> +16 sigma)
#define QCAP 1536           // quarter(64-node) capacity (mean 1024, sigma 32 -> +16 sigma)

typedef __attribute__((ext_vector_type(8))) short bf16x8;   // 8 bf16 = 4 VGPR
typedef __attribute__((ext_vector_type(4))) float f32x4;    // MFMA acc

static __device__ __forceinline__ unsigned short f2bf(float f) {
    union { float f; unsigned int u; } v; v.f = f;
    unsigned int r = (v.u + 0x7FFFu + ((v.u >> 16) & 1u)) >> 16;  // RNE
    return (unsigned short)r;
}
static __device__ __forceinline__ float bf2f(unsigned short h) {
    union { unsigned int u; float f; } v; v.u = ((unsigned int)h) << 16;
    return v.f;
}

// ------------------------------------------------------------------ front
// One kernel, independent block-range jobs (no intra-kernel dependencies):
//   [0, 157)       : edge binning — sort 4096-edge chunk by dst>>8 in LDS,
//                    write sorted recs (coalesced) + per-bucket offsets lmat
//   [157, 2669)    : x -> bf16 (NPAD rows; pad rows = 0)
//   [2669, 3181)   : W1/W2/Wres transpose+convert -> w1t|w2t|wrt (concat)
//   [3181, 3193)   : hb pad rows = 0 (192 rows)
// Record: (dst & 255) << 16 | src   (src < 65536)
#define FRONT_GRID 3193
__global__ __launch_bounds__(256) void k_front(
    const float* __restrict__ x,
    const float* __restrict__ W1, const float* __restrict__ W2,
    const float* __restrict__ Wres, const int* __restrict__ ei,
    ushort* __restrict__ xb, ushort* __restrict__ wt_all,
    unsigned int* __restrict__ recs, int* __restrict__ lmat,
    ushort* __restrict__ hb) {
    __shared__ unsigned int SM[4096 + 480 + 256];    // 19.3 KB, binning branch only
    int b = blockIdx.x, tid = threadIdx.x;
    if (b < NBIN) {                                  // ---- edge binning
        unsigned int* lrec = SM;
        int* cnt    = (int*)(SM + 4096);
        int* lstart = cnt + 160;
        int* lcur   = lstart + 160;
        int* sw     = lcur + 160;                    // [256]
        int e0 = b * 4096;
        int ns = min(e0 + 4096, EE) - e0;

        if (tid < NBIN) cnt[tid] = 0;
        __syncthreads();
        for (int s = tid; s < ns; s += 256)
            atomicAdd(&cnt[ei[EE + e0 + s] >> 8], 1);
        __syncthreads();
        sw[tid] = (tid < NBIN) ? cnt[tid] : 0;
        __syncthreads();
        for (int off = 1; off < 256; off <<= 1) {
            int add = (tid >= off) ? sw[tid - off] : 0;
            __syncthreads();
            sw[tid] += add;
            __syncthreads();
        }
        if (tid < NBIN) {
            int st = sw[tid] - cnt[tid];
            lstart[tid] = st;
            lcur[tid] = st;
        }
        __syncthreads();
        for (int s = tid; s < ns; s += 256) {
            int e = e0 + s;
            int src = ei[e];
            int dst = ei[EE + e];
            int p = atomicAdd(&lcur[dst >> 8], 1);
            lrec[p] = ((unsigned int)(dst & 255) << 16) | (unsigned int)src;
        }
        __syncthreads();
        for (int s = tid; s < ns; s += 256)          // coalesced sorted chunk
            recs[b * 4096 + s] = lrec[s];
        if (tid < NBIN + 1)
            lmat[b * 158 + tid] = (tid < NBIN) ? lstart[tid] : ns;
    } else if (b < 2669) {                           // ---- x convert
        int i = (b - NBIN) * 256 + tid;              // elem8 index
        int row = i >> 4;
        uint4 o = {0, 0, 0, 0};
        if (row < NN) {
            const float4* xp = (const float4*)x + (size_t)i * 2;
            float4 a = xp[0], c = xp[1];
            o.x = (unsigned)f2bf(a.x) | ((unsigned)f2bf(a.y) << 16);
            o.y = (unsigned)f2bf(a.z) | ((unsigned)f2bf(a.w) << 16);
            o.z = (unsigned)f2bf(c.x) | ((unsigned)f2bf(c.y) << 16);
            o.w = (unsigned)f2bf(c.z) | ((unsigned)f2bf(c.w) << 16);
        }
        *(uint4*)(xb + (size_t)i * 8) = o;           // i < NPAD*16 by grid
    } else if (b < 3181) {                           // ---- weight transposes
        int j = (b - 2669) * 256 + tid;              // concat index
        if (j < 32768) {                             // w1t [256][128]
            int c = j >> 7, r = j & 127;
            wt_all[j] = f2bf(W1[r * KDOUT + c]);
        } else if (j < 98304) {                      // w2t [256][256]
            int j2 = j - 32768;
            int c = j2 >> 8, r = j2 & 255;
            wt_all[j] = f2bf(W2[r * KDOUT + c]);
        } else {                                     // wrt [256][128]
            int j3 = j - 98304;
            int c = j3 >> 7, r = j3 & 127;
            wt_all[j] = f2bf(Wres[r * KDOUT + c]);
        }
    } else {                                         // ---- hb pad rows = 0
        int idx = (b - 3181) * 256 + tid;            // 3072 uint4 = 48 KB
        ((uint4*)(hb + (size_t)NN * KDIN))[idx] = (uint4){0, 0, 0, 0};
    }
}

// ---------------- aggregate: line-granular gather (pack + sort + reg gather)
// Grid NBIN*8: blockIdx = b*8 + nq*2 + qh  (nq: node-quarter of 64 nodes,
// qh: dim-HALF of 128 B = one full L2 cacheline). 8 lanes/record read one
// whole 128 B line -> each line fetched once (round-13's 64 B quarters
// fetched every line twice across blocks).
#define ACC8(arr_, v_)                                                          \
    arr_[0] += bf2f((ushort)((v_).x & 0xffff)); arr_[1] += bf2f((ushort)((v_).x >> 16)); \
    arr_[2] += bf2f((ushort)((v_).y & 0xffff)); arr_[3] += bf2f((ushort)((v_).y >> 16)); \
    arr_[4] += bf2f((ushort)((v_).z & 0xffff)); arr_[5] += bf2f((ushort)((v_).z >> 16)); \
    arr_[6] += bf2f((ushort)((v_).w & 0xffff)); arr_[7] += bf2f((ushort)((v_).w >> 16));

#define XROW(n_) (*((const uint4*)(xb + (size_t)(n_) * KDIN) + qoff))

__global__ __launch_bounds__(256) void k_aggE(
    const unsigned int* __restrict__ recs, const int* __restrict__ lmat,
    const ushort* __restrict__ xb, const float* __restrict__ eps,
    ushort* __restrict__ hb) {
    __shared__ unsigned int lrec[BCAP];              // 20 KB
    __shared__ ushort lsrc[QCAP];                    // 3 KB
    __shared__ int lcnt[64], lst[64], lcur[64];
    __shared__ int sw[256];
    int tid = threadIdx.x;
    int bi = blockIdx.x;
    int b = bi >> 3, nq = (bi >> 1) & 3, qh = bi & 1;
    int wid = tid >> 6, lane = tid & 63;

    // ---- segment-length scan (chunk-order prefix for pack offsets)
    int len0 = 0;
    if (tid < NBIN) len0 = lmat[tid * 158 + b + 1] - lmat[tid * 158 + b];
    sw[tid] = len0;
    __syncthreads();
    for (int off = 1; off < 256; off <<= 1) {
        int add = (tid >= off) ? sw[tid - off] : 0;
        __syncthreads();
        sw[tid] += add;
        __syncthreads();
    }
    int ctot = sw[255];

    // ---- coalesced pack: one wave per chunk, lanes along the segment
    for (int c = wid; c < NBIN; c += 4) {
        int s0 = lmat[c * 158 + b];
        int len = lmat[c * 158 + b + 1] - s0;
        int pofs = sw[c] - len;                      // exclusive prefix
        const unsigned int* seg = recs + c * 4096 + s0;
        for (int i = lane; i < len; i += 64)
            lrec[pofs + i] = seg[i];
    }
    if (tid < 64) lcnt[tid] = 0;
    __syncthreads();

    // ---- counting-sort this node-quarter by dst low-6
    for (int s = tid; s < ctot; s += 256) {
        int d8 = lrec[s] >> 16;
        if ((d8 >> 6) == nq) atomicAdd(&lcnt[d8 & 63], 1);
    }
    __syncthreads();
    sw[tid] = (tid < 64) ? lcnt[tid] : 0;
    __syncthreads();
    for (int off = 1; off < 64; off <<= 1) {
        int add = (tid >= off) ? sw[tid - off] : 0;
        __syncthreads();
        sw[tid] += add;
        __syncthreads();
    }
    if (tid < 64) {
        int e = sw[tid] - lcnt[tid];
        lst[tid] = e;
        lcur[tid] = e;
    }
    __syncthreads();
    for (int s = tid; s < ctot; s += 256) {
        unsigned int r = lrec[s];
        int d8 = r >> 16;
        if ((d8 >> 6) == nq) {
            int p = atomicAdd(&lcur[d8 & 63], 1);
            lsrc[p] = (ushort)(r & 0xffff);
        }
    }
    __syncthreads();

    // ---- gather: 32 groups x 8 lanes (128 B = full line per record)
    int g = tid >> 3, lane8 = tid & 7;
    int qoff = qh * 8 + lane8;                       // uint4 index within row
    float s1 = 1.0f + eps[0];
    for (int it = 0; it < 2; ++it) {
        int d = g + it * 32;                         // d in [0, 64)
        int node = b * 256 + nq * 64 + d;
        if (node >= NN) continue;
        int st = lst[d], en = st + lcnt[d];
        uint4 me = XROW(node);
        float a[8], a2[8];
#pragma unroll
        for (int i = 0; i < 8; ++i) a2[i] = 0.f;     // ACC8 accumulates: must init
        ACC8(a2, me);                                 // a2 = x[node]
#pragma unroll
        for (int i = 0; i < 8; ++i) { a[i] = a2[i] * s1; a2[i] = 0.f; }
        int e = st;
        for (; e + 1 < en; e += 2) {                 // 2 loads in flight
            int sA = lsrc[e], sB = lsrc[e + 1];
            uint4 v0 = XROW(sA);
            uint4 v1 = XROW(sB);
            ACC8(a, v0);
            ACC8(a2, v1);
        }
        if (e < en) {
            uint4 v0 = XROW(lsrc[e]);
            ACC8(a, v0);
        }
#pragma unroll
        for (int i = 0; i < 8; ++i) a[i] += a2[i];
        uint4 o;
        o.x = (unsigned)f2bf(a[0]) | ((unsigned)f2bf(a[1]) << 16);
        o.y = (unsigned)f2bf(a[2]) | ((unsigned)f2bf(a[3]) << 16);
        o.z = (unsigned)f2bf(a[4]) | ((unsigned)f2bf(a[5]) << 16);
        o.w = (unsigned)f2bf(a[6]) | ((unsigned)f2bf(a[7]) << 16);
        *((uint4*)(hb + (size_t)node * KDIN) + qoff) = o;
    }
}

// ------------------------------------------------------------ MFMA GEMMs
// W^T column slice staged in LDS, XOR-swizzled: byte ^= (col&7)<<4.
// A-fragments loaded directly from global (L3-resident, read once per block).

#define STAGE_WT(Wt_, Kc_, K2_, TPB_)                                           \
    for (int id = tid; id < BNT * (K2_) / 16; id += (TPB_)) {                   \
        int c = id / ((K2_) / 16);                                              \
        int koff = (id % ((K2_) / 16)) * 16;                                    \
        uint4 v = *(const uint4*)((const char*)((Wt_) + (size_t)(ncol0 + c) * (Kc_)) + koff); \
        *(uint4*)((char*)s + c * (K2_) + (koff ^ ((c & 7) << 4))) = v;          \
    }

#define MM_LOOP(A_, Kc_, K2_, acc0_, acc1_)                                     \
    {                                                                           \
        const char* a0p = (const char*)((A_) + (size_t)r0 * (Kc_)) + lq * 16;   \
        const char* a1p = a0p + 16 * (Kc_) * 2;                                 \
        for (int k0 = 0; k0 < (Kc_); k0 += 32) {                                \
            bf16x8 a0 = *(const bf16x8*)(a0p + k0 * 2);                         \
            bf16x8 a1 = *(const bf16x8*)(a1p + k0 * 2);                         \
            int kb = (k0 + lq * 8) * 2;                                         \
            _Pragma("unroll")                                                   \
            for (int nt = 0; nt < 8; ++nt) {                                    \
                int c = nt * 16 + l15;                                          \
                bf16x8 b = *(const bf16x8*)((const char*)s + c * (K2_) + (kb ^ ((c & 7) << 4))); \
                acc0_[nt] = __builtin_amdgcn_mfma_f32_16x16x32_bf16(a0, b, acc0_[nt], 0, 0, 0); \
                acc1_[nt] = __builtin_amdgcn_mfma_f32_16x16x32_bf16(a1, b, acc1_[nt], 0, 0, 0); \
            }                                                                   \
        }                                                                       \
    }

#define BNT 128

// GEMM1: h1 = relu(bn1(h @ W1 + b1))   [NPAD,128]x[128,256] -> bf16 [NPAD,256]
// 256 threads = 4 waves, BM=128, grid (NPAD/128)*2.
__global__ __launch_bounds__(256) void k_mm1(
    const ushort* __restrict__ A, const ushort* __restrict__ Wt,
    const float* __restrict__ bb, const float* __restrict__ g,
    const float* __restrict__ bt, const float* __restrict__ m,
    const float* __restrict__ vv, ushort* __restrict__ C) {
    __shared__ ushort s[BNT * 128];                  // 32 KB
    int tid = threadIdx.x;
    int bm = blockIdx.x >> 1, bn = blockIdx.x & 1;
    int ncol0 = bn * BNT;
    STAGE_WT(Wt, 128, 256, 256);
    __syncthreads();
    int wid = tid >> 6, lane = tid & 63;
    int l15 = lane & 15, lq = lane >> 4;
    int r0 = bm * 128 + wid * 32 + l15;
    f32x4 acc0[8] = {}, acc1[8] = {};
    MM_LOOP(A, 128, 256, acc0, acc1);
#pragma unroll
    for (int nt = 0; nt < 8; ++nt) {
        int col = ncol0 + nt * 16 + l15;
        float sc = g[col] * rsqrtf(vv[col] + 1e-5f);
        float bo = (bb[col] - m[col]) * sc + bt[col];
        int rb = bm * 128 + wid * 32 + lq * 4;
#pragma unroll
        for (int r = 0; r < 4; ++r) {
            C[(size_t)(rb + r) * KDOUT + col] = f2bf(fmaxf(acc0[nt][r] * sc + bo, 0.f));
            C[(size_t)(rb + 16 + r) * KDOUT + col] = f2bf(fmaxf(acc1[nt][r] * sc + bo, 0.f));
        }
    }
}

// GEMM2 fused: out = relu( relu(bn2(h1 @ W2 + b2)) + x @ Wres )
// 512 threads = 8 waves, BM=256 (same 64 KB LDS -> 16 waves/CU vs 8 before).
__global__ __launch_bounds__(512) void k_mm2(
    const ushort* __restrict__ H1, const ushort* __restrict__ W2t,
    const ushort* __restrict__ X, const ushort* __restrict__ Wrt,
    const float* __restrict__ bb, const float* __restrict__ g,
    const float* __restrict__ bt, const float* __restrict__ m,
    const float* __restrict__ vv, float* __restrict__ OUT) {
    __shared__ ushort s[BNT * 256];                  // 64 KB
    int tid = threadIdx.x;
    int bm = blockIdx.x >> 1, bn = blockIdx.x & 1;
    int ncol0 = bn * BNT;
    int wid = tid >> 6, lane = tid & 63;             // wid in [0,8)
    int l15 = lane & 15, lq = lane >> 4;
    int r0 = bm * 256 + wid * 32 + l15;

    STAGE_WT(W2t, 256, 512, 512);                    // phase 1: h1 @ W2
    __syncthreads();
    f32x4 acc0[8] = {}, acc1[8] = {};
    MM_LOOP(H1, 256, 512, acc0, acc1);

    __syncthreads();                                 // re-stage: Wres^T
    STAGE_WT(Wrt, 128, 256, 512);
    __syncthreads();
    f32x4 acd0[8] = {}, acd1[8] = {};
    MM_LOOP(X, 128, 256, acd0, acd1);

#pragma unroll
    for (int nt = 0; nt < 8; ++nt) {
        int col = ncol0 + nt * 16 + l15;
        float sc = g[col] * rsqrtf(vv[col] + 1e-5f);
        float bo = (bb[col] - m[col]) * sc + bt[col];
        int rb = bm * 256 + wid * 32 + lq * 4;
#pragma unroll
        for (int r = 0; r < 4; ++r) {
            int row0 = rb + r, row1 = rb + 16 + r;
            float t0 = fmaxf(acc0[nt][r] * sc + bo, 0.f);
            float t1 = fmaxf(acc1[nt][r] * sc + bo, 0.f);
            if (row0 < NN) OUT[(size_t)row0 * KDOUT + col] = fmaxf(t0 + acd0[nt][r], 0.f);
            if (row1 < NN) OUT[(size_t)row1 * KDOUT + col] = fmaxf(t1 + acd1[nt][r], 0.f);
        }
    }
}

// ------------------------------------------------------------------- launch
extern "C" void kernel_launch(void* const* d_in, const int* in_sizes, int n_in,
                              void* d_out, int out_size, void* d_ws, size_t ws_size,
                              hipStream_t stream) {
    const float* x    = (const float*)d_in[0];
    const int*   ei   = (const int*)d_in[1];
    const float* eps  = (const float*)d_in[2];
    const float* W1   = (const float*)d_in[3];
    const float* b1   = (const float*)d_in[4];
    const float* g1   = (const float*)d_in[5];
    const float* bt1  = (const float*)d_in[6];
    const float* m1   = (const float*)d_in[7];
    const float* v1   = (const float*)d_in[8];
    const float* W2   = (const float*)d_in[9];
    const float* b2   = (const float*)d_in[10];
    const float* g2   = (const float*)d_in[11];
    const float* bt2  = (const float*)d_in[12];
    const float* m2   = (const float*)d_in[13];
    const float* v2   = (const float*)d_in[14];
    const float* Wres = (const float*)d_in[15];
    float* out = (float*)d_out;

    char* w = (char*)d_ws;
    ushort* xb  = (ushort*)w;                 w += (size_t)NPAD * KDIN * 2;   // 10.3 MB
    ushort* hb  = (ushort*)w;                 w += (size_t)NPAD * KDIN * 2;   // 10.3 MB
    ushort* h1b = (ushort*)w;                 w += (size_t)NPAD * KDOUT * 2;  // 20.6 MB
    ushort* w1t = (ushort*)w;                 w += 256 * 128 * 2;
    ushort* w2t = (ushort*)w;                 w += 256 * 256 * 2;
    ushort* wrt = (ushort*)w;                 w += 256 * 128 * 2;
    unsigned int* recs = (unsigned int*)w;    w += (size_t)NBIN * 4096 * 4;   // 2.57 MB
    int* lmat   = (int*)w;                    w += (size_t)NBIN * 158 * 4;    // 99 KB

    // front: edge binning || x->bf16 || weight transposes || hb pad zero
    k_front<<<FRONT_GRID, 256, 0, stream>>>(x, W1, W2, Wres, ei, xb, w1t,
                                            recs, lmat, hb);
    // aggregate: per (bucket, node-quarter, dim-half) — line-granular gather
    k_aggE<<<NBIN * 8, 256, 0, stream>>>(recs, lmat, xb, eps, hb);

    k_mm1<<<(NPAD / 128) * 2, 256, 0, stream>>>(hb, w1t, b1, g1, bt1, m1, v1, h1b);
    k_mm2<<<(NPAD / 256) * 2, 512, 0, stream>>>(h1b, w2t, xb, wrt, b2, g2, bt2,
                                                m2, v2, out);
}